// Round 6
// baseline (544.966 us; speedup 1.0000x reference)
//
#include <hip/hip_runtime.h>

typedef unsigned int u32;
typedef unsigned short u16;
typedef short bf16x8 __attribute__((ext_vector_type(8)));
typedef float f32x4 __attribute__((ext_vector_type(4)));
typedef u32 u32x4 __attribute__((ext_vector_type(4)));

#define HBLK 256  // blocks in hist/scatter2 pass

__device__ __forceinline__ u16 f2bf(float f) {
  u32 u = __float_as_uint(f);
  u = (u + 0x7FFFu + ((u >> 16) & 1u)) >> 16;
  return (u16)u;
}
__device__ __forceinline__ float bf2f(u32 h) { return __uint_as_float(h << 16); }

// ---------------- CSR build: bucket sort by dst ----------------
// bucket = dst >> 7 (128 nodes per bucket)
__global__ void hist_kernel(const int* __restrict__ dst, int* __restrict__ hist,
                            int E, int nbuk, int chunk) {
  __shared__ int h[1024];
  for (int i = threadIdx.x; i < nbuk; i += 256) h[i] = 0;
  __syncthreads();
  int b0 = blockIdx.x * chunk, b1 = min(b0 + chunk, E);
  for (int e = b0 + threadIdx.x; e < b1; e += 256)
    atomicAdd(&h[dst[e] >> 7], 1);
  __syncthreads();
  for (int i = threadIdx.x; i < nbuk; i += 256)
    hist[i * HBLK + blockIdx.x] = h[i];  // [bucket][block]
}

__global__ void scan_local(const int* __restrict__ in, int* __restrict__ out,
                           int* __restrict__ bsum, int n) {
  __shared__ int s[256];
  int tid = threadIdx.x;
  int i = blockIdx.x * 256 + tid;
  int v = (i < n) ? in[i] : 0;
  s[tid] = v;
  __syncthreads();
  for (int off = 1; off < 256; off <<= 1) {
    int t = (tid >= off) ? s[tid - off] : 0;
    __syncthreads();
    s[tid] += t;
    __syncthreads();
  }
  if (i < n) out[i] = s[tid] - v;  // local exclusive
  if (tid == 255) bsum[blockIdx.x] = s[255];
}

// merged: each block computes its global offset (reduce of bsum[0..b)) and adds
__global__ void scan_fix(int* __restrict__ a, const int* __restrict__ bsum, int n) {
  __shared__ int red[256];
  int tid = threadIdx.x, b = blockIdx.x;
  int s = 0;
  for (int k = tid; k < b; k += 256) s += bsum[k];
  red[tid] = s;
  __syncthreads();
  for (int off = 128; off; off >>= 1) {
    if (tid < off) red[tid] += red[tid + off];
    __syncthreads();
  }
  int i = b * 256 + tid;
  if (i < n) a[i] += red[0];
}

// partition edges into bucket-ordered part[]: packed (dstLow7<<25 | src)
__global__ void scatter2_kernel(const int* __restrict__ src, const int* __restrict__ dst,
                                const int* __restrict__ hist_s, u32* __restrict__ part,
                                int E, int nbuk, int chunk) {
  __shared__ int cur[1024];
  for (int i = threadIdx.x; i < nbuk; i += 256)
    cur[i] = hist_s[i * HBLK + blockIdx.x];
  __syncthreads();
  int b0 = blockIdx.x * chunk, b1 = min(b0 + chunk, E);
  for (int e = b0 + threadIdx.x; e < b1; e += 256) {
    int d = dst[e];
    int pos = atomicAdd(&cur[d >> 7], 1);
    part[pos] = (u32)src[e] | ((u32)(d & 127) << 25);
  }
}

// per-bucket: count per node, scan -> roff, scatter src into contiguous csr window
__global__ void scatter3_kernel(const u32* __restrict__ part, const int* __restrict__ hist_s,
                                int* __restrict__ roff, int* __restrict__ csr,
                                int E, int nbuk, int n) {
  int b = blockIdx.x;
  int tid = threadIdx.x;
  int base = hist_s[b * HBLK];
  int end = (b + 1 < nbuk) ? hist_s[(b + 1) * HBLK] : E;
  __shared__ int cnt[128];
  __shared__ int s[128];
  __shared__ int cur[128];
  if (tid < 128) cnt[tid] = 0;
  __syncthreads();
  for (int e = base + tid; e < end; e += 256)
    atomicAdd(&cnt[part[e] >> 25], 1);
  __syncthreads();
  if (tid < 128) s[tid] = cnt[tid];
  __syncthreads();
  for (int off = 1; off < 128; off <<= 1) {
    int t = (tid >= off && tid < 128) ? s[tid - off] : 0;
    __syncthreads();
    if (tid < 128) s[tid] += t;
    __syncthreads();
  }
  if (tid < 128) {
    int excl = s[tid] - cnt[tid];
    cur[tid] = base + excl;
    int node = b * 128 + tid;
    if (node < n) roff[node] = base + excl;
  }
  if (b == 0 && tid == 0) roff[n] = E;
  __syncthreads();
  for (int e = base + tid; e < end; e += 256) {
    u32 p = part[e];
    int pos = atomicAdd(&cur[p >> 25], 1);
    csr[pos] = (int)(p & 0x1FFFFFFu);
  }
}

// ---------------- layer 1: fused mean + rank-2 MLP ----------------
// one wave per node: 64-lane gather-reduce of x[src], then 2 features/lane
__global__ void meanh1_kernel(const int* __restrict__ csr, const int* __restrict__ roff,
                              const float* __restrict__ x,
                              const float* __restrict__ W1l, const float* __restrict__ W1r,
                              const float* __restrict__ b1, u32* __restrict__ h1, int n) {
  int wave = threadIdx.x >> 6, lane = threadIdx.x & 63;
  int i = blockIdx.x * 4 + wave;
  if (i >= n) return;
  int e0 = roff[i], e1 = roff[i + 1];
  float s = 0.f;
  for (int e = e0 + lane; e < e1; e += 64) s += x[csr[e]];
#pragma unroll
  for (int off = 1; off < 64; off <<= 1) s += __shfl_xor(s, off, 64);
  float m = s / (float)max(e1 - e0, 1);
  float xs = x[i];
  int j0 = lane * 2;
  float v0 = fmaxf(m * W1l[j0] + xs * W1r[j0] + b1[j0], 0.f);
  float v1 = fmaxf(m * W1l[j0 + 1] + xs * W1r[j0 + 1] + b1[j0 + 1], 0.f);
  h1[(size_t)i * 64 + lane] = (u32)f2bf(v0) | ((u32)f2bf(v1) << 16);
}

// pack both weight pairs into bf16 W^T layout; also zero pooled/gcnt
__global__ void wprep2_kernel(const float* __restrict__ W2l, const float* __restrict__ W2r,
                              const float* __restrict__ W3l, const float* __restrict__ W3r,
                              u16* __restrict__ wt2, u16* __restrict__ wt3,
                              float* __restrict__ pooled, int* __restrict__ gcnt) {
  int idx = blockIdx.x * 256 + threadIdx.x;  // 0..65535
  int which = idx >> 15, r = idx & 32767;
  int j = r >> 8, k = r & 255;
  if (which == 0) {
    float v = (k < 128) ? W2l[k * 128 + j] : W2r[(k - 128) * 128 + j];
    wt2[r] = f2bf(v);
  } else {
    float v = (k < 128) ? W3l[k * 128 + j] : W3r[(k - 128) * 128 + j];
    wt3[r] = f2bf(v);
  }
  if (idx < 8192) pooled[idx] = 0.f;
  if (idx < 64) gcnt[idx] = 0;
}

// ---------------- fused aggregation + MFMA layer ----------------
// h_out = relu([mean_agg(h_in) | h_in] @ [Wl; Wr] + b)
// Phase 1: each wave aggregates its 16 MFMA tile rows into LDS (padded stride).
// Phase 2: MFMA 16x16x32; A-left from LDS, A-right from global h_in,
//          B-fragments straight from L2-resident Wt (no weight LDS -> high occupancy).
__launch_bounds__(256)
__global__ void aggmm_kernel(const int* __restrict__ csr, const int* __restrict__ roff,
                             const u32* __restrict__ hin, const u16* __restrict__ Wt,
                             const float* __restrict__ bias, u16* __restrict__ Out, int n) {
  __shared__ u16 mean_lds[64 * 136];  // 64 rows, stride 136 u16 (272B -> 2-way-free banks)
  int wave = threadIdx.x >> 6, lane = threadIdx.x & 63;
  int grp = lane >> 4, li = lane & 15;
  int row0 = blockIdx.x * 64;
  for (int r = 0; r < 16; ++r) {
    int rb = wave * 16 + r;
    int i = row0 + rb;
    if (i < n) {
      int e0 = roff[i], e1 = roff[i + 1];
      float a[8] = {};
      int e = e0 + grp;
      for (; e + 12 < e1; e += 16) {
        int s0 = csr[e], s1 = csr[e + 4], s2 = csr[e + 8], s3 = csr[e + 12];
        u32x4 v0 = *(const u32x4*)(hin + (size_t)s0 * 64 + li * 4);
        u32x4 v1 = *(const u32x4*)(hin + (size_t)s1 * 64 + li * 4);
        u32x4 v2 = *(const u32x4*)(hin + (size_t)s2 * 64 + li * 4);
        u32x4 v3 = *(const u32x4*)(hin + (size_t)s3 * 64 + li * 4);
#pragma unroll
        for (int w = 0; w < 4; ++w) {
          a[2 * w]     += bf2f(v0[w] & 0xFFFFu) + bf2f(v1[w] & 0xFFFFu) +
                          bf2f(v2[w] & 0xFFFFu) + bf2f(v3[w] & 0xFFFFu);
          a[2 * w + 1] += bf2f(v0[w] >> 16) + bf2f(v1[w] >> 16) +
                          bf2f(v2[w] >> 16) + bf2f(v3[w] >> 16);
        }
      }
      for (; e + 4 < e1; e += 8) {
        int s0 = csr[e], s1 = csr[e + 4];
        u32x4 v0 = *(const u32x4*)(hin + (size_t)s0 * 64 + li * 4);
        u32x4 v1 = *(const u32x4*)(hin + (size_t)s1 * 64 + li * 4);
#pragma unroll
        for (int w = 0; w < 4; ++w) {
          a[2 * w]     += bf2f(v0[w] & 0xFFFFu) + bf2f(v1[w] & 0xFFFFu);
          a[2 * w + 1] += bf2f(v0[w] >> 16) + bf2f(v1[w] >> 16);
        }
      }
      if (e < e1) {
        int s0 = csr[e];
        u32x4 v0 = *(const u32x4*)(hin + (size_t)s0 * 64 + li * 4);
#pragma unroll
        for (int w = 0; w < 4; ++w) {
          a[2 * w]     += bf2f(v0[w] & 0xFFFFu);
          a[2 * w + 1] += bf2f(v0[w] >> 16);
        }
      }
#pragma unroll
      for (int w = 0; w < 8; ++w) {
        a[w] += __shfl_xor(a[w], 16, 64);
        a[w] += __shfl_xor(a[w], 32, 64);
      }
      if (grp == 0) {
        float inv = 1.f / (float)max(e1 - e0, 1);
        u32x4 o;
#pragma unroll
        for (int w = 0; w < 4; ++w)
          o[w] = (u32)f2bf(a[2 * w] * inv) | ((u32)f2bf(a[2 * w + 1] * inv) << 16);
        *(u32x4*)&mean_lds[rb * 136 + li * 8] = o;
      }
    } else if (grp == 0) {
      u32x4 z = {};
      *(u32x4*)&mean_lds[rb * 136 + li * 8] = z;
    }
  }
  __syncthreads();
  int quad = grp, l16 = li;
  int m = row0 + wave * 16 + l16;
  int mc = m < n ? m : (n - 1);
  f32x4 acc[8] = {};
#pragma unroll
  for (int s = 0; s < 4; ++s) {  // half 0: A = aggregated mean, from LDS
    bf16x8 a = *(const bf16x8*)&mean_lds[(wave * 16 + l16) * 136 + s * 32 + quad * 8];
    int chunk = (s << 2) + quad;
#pragma unroll
    for (int t = 0; t < 8; ++t) {
      int j = t * 16 + l16;
      bf16x8 b = *(const bf16x8*)(Wt + (size_t)j * 256 + chunk * 8);
      acc[t] = __builtin_amdgcn_mfma_f32_16x16x32_bf16(a, b, acc[t], 0, 0, 0);
    }
  }
  const u16* A = (const u16*)hin + (size_t)mc * 128;
#pragma unroll
  for (int s = 0; s < 4; ++s) {  // half 1: A = self features, from global
    bf16x8 a = *(const bf16x8*)(A + s * 32 + quad * 8);
    int chunk = 16 + (s << 2) + quad;
#pragma unroll
    for (int t = 0; t < 8; ++t) {
      int j = t * 16 + l16;
      bf16x8 b = *(const bf16x8*)(Wt + (size_t)j * 256 + chunk * 8);
      acc[t] = __builtin_amdgcn_mfma_f32_16x16x32_bf16(a, b, acc[t], 0, 0, 0);
    }
  }
  // C layout: col = lane&15, row = quad*4 + reg (m89-verified)
#pragma unroll
  for (int t = 0; t < 8; ++t) {
    int j = t * 16 + l16;
    float bj = bias[j];
#pragma unroll
    for (int r = 0; r < 4; ++r) {
      int mr = row0 + wave * 16 + quad * 4 + r;
      if (mr < n) {
        float v = acc[t][r] + bj;
        Out[(size_t)mr * 128 + j] = f2bf(fmaxf(v, 0.f));
      }
    }
  }
}

// ---------------- pooling (two-phase, parallel) ----------------
#define PB_NODES 256
__global__ void pool_partial(const int* __restrict__ batch, const u32* __restrict__ h3,
                             float* __restrict__ pooled, int* __restrict__ gcnt, int n) {
  int wave = threadIdx.x >> 6, lane = threadIdx.x & 63;
  int start = blockIdx.x * PB_NODES;
  int end = min(start + PB_NODES, n);
  float a0 = 0.f, a1 = 0.f;
  int gcur = -1, cnt = 0;
  for (int i = start + wave; i < end; i += 4) {
    int g = batch[i];
    if (g != gcur) {
      if (gcur >= 0) {
        atomicAdd(&pooled[gcur * 128 + lane * 2], a0);
        atomicAdd(&pooled[gcur * 128 + lane * 2 + 1], a1);
        if (lane == 0) atomicAdd(&gcnt[gcur], cnt);
      }
      gcur = g; a0 = 0.f; a1 = 0.f; cnt = 0;
    }
    u32 v = h3[(size_t)i * 64 + lane];
    a0 += bf2f(v & 0xFFFFu);
    a1 += bf2f(v >> 16);
    cnt++;
  }
  if (gcur >= 0) {
    atomicAdd(&pooled[gcur * 128 + lane * 2], a0);
    atomicAdd(&pooled[gcur * 128 + lane * 2 + 1], a1);
    if (lane == 0) atomicAdd(&gcnt[gcur], cnt);
  }
}

__global__ void head_kernel(const float* __restrict__ pooled, const int* __restrict__ gcnt,
                            const float* __restrict__ Wfc, const float* __restrict__ bfc,
                            float* __restrict__ out) {
  __shared__ float lg[64][10];
  int t = threadIdx.x;
  if (t < 640) {
    int g = t / 10, c = t % 10;
    float inv = 1.f / (float)max(gcnt[g], 1);
    float acc = bfc[c];
    for (int k = 0; k < 128; ++k) acc += pooled[g * 128 + k] * inv * Wfc[k * 10 + c];
    lg[g][c] = acc;
  }
  __syncthreads();
  if (t < 640) {
    int g = t / 10, c = t % 10;
    float mx = -1e30f;
    for (int q = 0; q < 10; ++q) mx = fmaxf(mx, lg[g][q]);
    float se = 0.f;
    for (int q = 0; q < 10; ++q) se += expf(lg[g][q] - mx);
    out[g * 10 + c] = lg[g][c] - mx - logf(se);
  }
}

extern "C" void kernel_launch(void* const* d_in, const int* in_sizes, int n_in,
                              void* d_out, int out_size, void* d_ws, size_t ws_size,
                              hipStream_t stream) {
  const float* x   = (const float*)d_in[0];
  const int* ei    = (const int*)d_in[1];
  const int* batch = (const int*)d_in[2];
  const float* W1l = (const float*)d_in[3];
  const float* W1r = (const float*)d_in[4];
  const float* b1  = (const float*)d_in[5];
  const float* W2l = (const float*)d_in[6];
  const float* W2r = (const float*)d_in[7];
  const float* b2  = (const float*)d_in[8];
  const float* W3l = (const float*)d_in[9];
  const float* W3r = (const float*)d_in[10];
  const float* b3  = (const float*)d_in[11];
  const float* Wfc = (const float*)d_in[12];
  const float* bfc = (const float*)d_in[13];
  float* out = (float*)d_out;
  int N = in_sizes[0];
  int E = in_sizes[1] / 2;
  const int* src = ei;
  const int* dst = ei + E;

  char* p = (char*)d_ws;
  auto alloc = [&](size_t bytes) { void* r = (void*)p; p += (bytes + 255) & ~(size_t)255; return r; };
  int* roff   = (int*)alloc((size_t)(N + 1) * 4);
  int* csr    = (int*)alloc((size_t)E * 4);
  u32* bufA   = (u32*)alloc((size_t)N * 64 * 4);  // h1 -> h3 (aliases hist early)
  u32* bufB   = (u32*)alloc((size_t)N * 64 * 4);  // h2       (aliases part early)
  u16* wt2    = (u16*)alloc(32768 * 2);
  u16* wt3    = (u16*)alloc(32768 * 2);
  float* pooled = (float*)alloc(64 * 128 * 4);
  int* gcnt   = (int*)alloc(64 * 4);
  int* bsum   = (int*)alloc(1024 * 4);

  // CSR-build-time aliases (strictly before meanh1/aggmm write bufA/bufB)
  int nbuk = (N + 127) >> 7;          // 782
  int* hist = (int*)bufA;             // nbuk*HBLK ints = 800 KB
  u32* part = (u32*)bufB;             // E u32 = 6.4 MB
  int chunk = (E + HBLK - 1) / HBLK;  // 6250
  int nH = nbuk * HBLK;               // 200192
  int nbH = (nH + 255) / 256;         // 782

  hist_kernel<<<HBLK, 256, 0, stream>>>(dst, hist, E, nbuk, chunk);
  scan_local<<<nbH, 256, 0, stream>>>(hist, hist, bsum, nH);
  scan_fix<<<nbH, 256, 0, stream>>>(hist, bsum, nH);
  scatter2_kernel<<<HBLK, 256, 0, stream>>>(src, dst, hist, part, E, nbuk, chunk);
  scatter3_kernel<<<nbuk, 256, 0, stream>>>(part, hist, roff, csr, E, nbuk, N);
  wprep2_kernel<<<256, 256, 0, stream>>>(W2l, W2r, W3l, W3r, wt2, wt3, pooled, gcnt);
  meanh1_kernel<<<(N + 3) / 4, 256, 0, stream>>>(csr, roff, x, W1l, W1r, b1, bufA, N);
  aggmm_kernel<<<(N + 63) / 64, 256, 0, stream>>>(csr, roff, bufA, wt2, b2, (u16*)bufB, N);
  aggmm_kernel<<<(N + 63) / 64, 256, 0, stream>>>(csr, roff, bufB, wt3, b3, (u16*)bufA, N);
  pool_partial<<<(N + PB_NODES - 1) / PB_NODES, 256, 0, stream>>>(batch, bufA, pooled, gcnt, N);
  head_kernel<<<1, 640, 0, stream>>>(pooled, gcnt, Wfc, bfc, out);
}

// Round 7
// 452.969 us; speedup vs baseline: 1.2031x; 1.2031x over previous
//
#include <hip/hip_runtime.h>

typedef unsigned int u32;
typedef unsigned short u16;
typedef short bf16x8 __attribute__((ext_vector_type(8)));
typedef float f32x4 __attribute__((ext_vector_type(4)));
typedef u32 u32x4 __attribute__((ext_vector_type(4)));

#define HBLK 256  // blocks in hist/scatter2 pass

__device__ __forceinline__ u16 f2bf(float f) {
  u32 u = __float_as_uint(f);
  u = (u + 0x7FFFu + ((u >> 16) & 1u)) >> 16;
  return (u16)u;
}
__device__ __forceinline__ float bf2f(u32 h) { return __uint_as_float(h << 16); }

// ---------------- CSR build: bucket sort by dst ----------------
// bucket = dst >> 7 (128 nodes per bucket)
__global__ void hist_kernel(const int* __restrict__ dst, int* __restrict__ hist,
                            int E, int nbuk, int chunk) {
  __shared__ int h[1024];
  for (int i = threadIdx.x; i < nbuk; i += 256) h[i] = 0;
  __syncthreads();
  int b0 = blockIdx.x * chunk, b1 = min(b0 + chunk, E);
  for (int e = b0 + threadIdx.x; e < b1; e += 256)
    atomicAdd(&h[dst[e] >> 7], 1);
  __syncthreads();
  for (int i = threadIdx.x; i < nbuk; i += 256)
    hist[i * HBLK + blockIdx.x] = h[i];  // [bucket][block]
}

__global__ void scan_local(const int* __restrict__ in, int* __restrict__ out,
                           int* __restrict__ bsum, int n) {
  __shared__ int s[256];
  int tid = threadIdx.x;
  int i = blockIdx.x * 256 + tid;
  int v = (i < n) ? in[i] : 0;
  s[tid] = v;
  __syncthreads();
  for (int off = 1; off < 256; off <<= 1) {
    int t = (tid >= off) ? s[tid - off] : 0;
    __syncthreads();
    s[tid] += t;
    __syncthreads();
  }
  if (i < n) out[i] = s[tid] - v;  // local exclusive
  if (tid == 255) bsum[blockIdx.x] = s[255];
}

// merged: each block computes its global offset (reduce of bsum[0..b)) and adds
__global__ void scan_fix(int* __restrict__ a, const int* __restrict__ bsum, int n) {
  __shared__ int red[256];
  int tid = threadIdx.x, b = blockIdx.x;
  int s = 0;
  for (int k = tid; k < b; k += 256) s += bsum[k];
  red[tid] = s;
  __syncthreads();
  for (int off = 128; off; off >>= 1) {
    if (tid < off) red[tid] += red[tid + off];
    __syncthreads();
  }
  int i = b * 256 + tid;
  if (i < n) a[i] += red[0];
}

// partition edges into bucket-ordered part[]: packed (dstLow7<<25 | src)
__global__ void scatter2_kernel(const int* __restrict__ src, const int* __restrict__ dst,
                                const int* __restrict__ hist_s, u32* __restrict__ part,
                                int E, int nbuk, int chunk) {
  __shared__ int cur[1024];
  for (int i = threadIdx.x; i < nbuk; i += 256)
    cur[i] = hist_s[i * HBLK + blockIdx.x];
  __syncthreads();
  int b0 = blockIdx.x * chunk, b1 = min(b0 + chunk, E);
  for (int e = b0 + threadIdx.x; e < b1; e += 256) {
    int d = dst[e];
    int pos = atomicAdd(&cur[d >> 7], 1);
    part[pos] = (u32)src[e] | ((u32)(d & 127) << 25);
  }
}

// per-bucket: count per node, scan -> roff, scatter src into contiguous csr window
__global__ void scatter3_kernel(const u32* __restrict__ part, const int* __restrict__ hist_s,
                                int* __restrict__ roff, int* __restrict__ csr,
                                int E, int nbuk, int n) {
  int b = blockIdx.x;
  int tid = threadIdx.x;
  int base = hist_s[b * HBLK];
  int end = (b + 1 < nbuk) ? hist_s[(b + 1) * HBLK] : E;
  __shared__ int cnt[128];
  __shared__ int s[128];
  __shared__ int cur[128];
  if (tid < 128) cnt[tid] = 0;
  __syncthreads();
  for (int e = base + tid; e < end; e += 256)
    atomicAdd(&cnt[part[e] >> 25], 1);
  __syncthreads();
  if (tid < 128) s[tid] = cnt[tid];
  __syncthreads();
  for (int off = 1; off < 128; off <<= 1) {
    int t = (tid >= off && tid < 128) ? s[tid - off] : 0;
    __syncthreads();
    if (tid < 128) s[tid] += t;
    __syncthreads();
  }
  if (tid < 128) {
    int excl = s[tid] - cnt[tid];
    cur[tid] = base + excl;
    int node = b * 128 + tid;
    if (node < n) roff[node] = base + excl;
  }
  if (b == 0 && tid == 0) roff[n] = E;
  __syncthreads();
  for (int e = base + tid; e < end; e += 256) {
    u32 p = part[e];
    int pos = atomicAdd(&cur[p >> 25], 1);
    csr[pos] = (int)(p & 0x1FFFFFFu);
  }
}

// ---------------- layer 1: fused mean + rank-2 MLP ----------------
// one wave per node: 64-lane gather-reduce of x[src], then 2 features/lane
__global__ void meanh1_kernel(const int* __restrict__ csr, const int* __restrict__ roff,
                              const float* __restrict__ x,
                              const float* __restrict__ W1l, const float* __restrict__ W1r,
                              const float* __restrict__ b1, u32* __restrict__ h1, int n) {
  int wave = threadIdx.x >> 6, lane = threadIdx.x & 63;
  int i = blockIdx.x * 4 + wave;
  if (i >= n) return;
  int e0 = roff[i], e1 = roff[i + 1];
  float s = 0.f;
  for (int e = e0 + lane; e < e1; e += 64) s += x[csr[e]];
#pragma unroll
  for (int off = 1; off < 64; off <<= 1) s += __shfl_xor(s, off, 64);
  float m = s / (float)max(e1 - e0, 1);
  float xs = x[i];
  int j0 = lane * 2;
  float v0 = fmaxf(m * W1l[j0] + xs * W1r[j0] + b1[j0], 0.f);
  float v1 = fmaxf(m * W1l[j0 + 1] + xs * W1r[j0 + 1] + b1[j0 + 1], 0.f);
  h1[(size_t)i * 64 + lane] = (u32)f2bf(v0) | ((u32)f2bf(v1) << 16);
}

// pack both weight pairs into bf16 W^T layout; also zero pooled/gcnt
__global__ void wprep2_kernel(const float* __restrict__ W2l, const float* __restrict__ W2r,
                              const float* __restrict__ W3l, const float* __restrict__ W3r,
                              u16* __restrict__ wt2, u16* __restrict__ wt3,
                              float* __restrict__ pooled, int* __restrict__ gcnt) {
  int idx = blockIdx.x * 256 + threadIdx.x;  // 0..65535
  int which = idx >> 15, r = idx & 32767;
  int j = r >> 8, k = r & 255;
  if (which == 0) {
    float v = (k < 128) ? W2l[k * 128 + j] : W2r[(k - 128) * 128 + j];
    wt2[r] = f2bf(v);
  } else {
    float v = (k < 128) ? W3l[k * 128 + j] : W3r[(k - 128) * 128 + j];
    wt3[r] = f2bf(v);
  }
  if (idx < 8192) pooled[idx] = 0.f;
  if (idx < 64) gcnt[idx] = 0;
}

// generic mean-aggregation of bf16 feature rows over CSR.
// 4x16-lane groups each gather a different edge's 256B row via dwordx4;
// 4-deep unroll -> 16 edges in flight per wave (cascade 2-deep / 1-deep tail).
__global__ void agg_kernel(const int* __restrict__ csr, const int* __restrict__ roff,
                           const u32* __restrict__ hin, u32* __restrict__ outv, int n) {
  int wave = threadIdx.x >> 6, lane = threadIdx.x & 63;
  int i = blockIdx.x * 4 + wave;
  if (i >= n) return;
  int grp = lane >> 4, li = lane & 15;
  int e0 = roff[i], e1 = roff[i + 1];
  float a[8] = {};
  int e = e0 + grp;
  for (; e + 12 < e1; e += 16) {
    int s0 = csr[e], s1 = csr[e + 4], s2 = csr[e + 8], s3 = csr[e + 12];
    u32x4 v0 = *(const u32x4*)(hin + (size_t)s0 * 64 + li * 4);
    u32x4 v1 = *(const u32x4*)(hin + (size_t)s1 * 64 + li * 4);
    u32x4 v2 = *(const u32x4*)(hin + (size_t)s2 * 64 + li * 4);
    u32x4 v3 = *(const u32x4*)(hin + (size_t)s3 * 64 + li * 4);
#pragma unroll
    for (int w = 0; w < 4; ++w) {
      a[2 * w]     += bf2f(v0[w] & 0xFFFFu) + bf2f(v1[w] & 0xFFFFu) +
                      bf2f(v2[w] & 0xFFFFu) + bf2f(v3[w] & 0xFFFFu);
      a[2 * w + 1] += bf2f(v0[w] >> 16) + bf2f(v1[w] >> 16) +
                      bf2f(v2[w] >> 16) + bf2f(v3[w] >> 16);
    }
  }
  for (; e + 4 < e1; e += 8) {
    int s0 = csr[e], s1 = csr[e + 4];
    u32x4 v0 = *(const u32x4*)(hin + (size_t)s0 * 64 + li * 4);
    u32x4 v1 = *(const u32x4*)(hin + (size_t)s1 * 64 + li * 4);
#pragma unroll
    for (int w = 0; w < 4; ++w) {
      a[2 * w]     += bf2f(v0[w] & 0xFFFFu) + bf2f(v1[w] & 0xFFFFu);
      a[2 * w + 1] += bf2f(v0[w] >> 16) + bf2f(v1[w] >> 16);
    }
  }
  if (e < e1) {
    int s0 = csr[e];
    u32x4 v0 = *(const u32x4*)(hin + (size_t)s0 * 64 + li * 4);
#pragma unroll
    for (int w = 0; w < 4; ++w) {
      a[2 * w]     += bf2f(v0[w] & 0xFFFFu);
      a[2 * w + 1] += bf2f(v0[w] >> 16);
    }
  }
#pragma unroll
  for (int w = 0; w < 8; ++w) {
    a[w] += __shfl_xor(a[w], 16, 64);
    a[w] += __shfl_xor(a[w], 32, 64);
  }
  if (grp == 0) {
    float inv = 1.f / (float)max(e1 - e0, 1);
    u32x4 o;
#pragma unroll
    for (int w = 0; w < 4; ++w)
      o[w] = (u32)f2bf(a[2 * w] * inv) | ((u32)f2bf(a[2 * w + 1] * inv) << 16);
    *(u32x4*)(outv + (size_t)i * 64 + li * 4) = o;
  }
}

// h_next = relu([mean | h] @ [Wl; Wr] + b), MFMA 16x16x32 bf16.
// B-fragments read directly from L2-resident Wt (64KB) -> no LDS, high occupancy.
// In-place safe: each wave writes only the rows it read for A.
__launch_bounds__(256)
__global__ void mm_kernel(const u16* Aleft, const u16* Aright,
                          const u16* __restrict__ Wt, const float* __restrict__ bias,
                          u16* Out, int n) {
  int wave = threadIdx.x >> 6;
  int lane = threadIdx.x & 63;
  int quad = lane >> 4, l16 = lane & 15;
  int row0 = blockIdx.x * 64 + wave * 16;
  int m = row0 + l16;
  int mc = m < n ? m : (n - 1);
  f32x4 acc[8] = {};
  const u16* Ah[2] = {Aleft, Aright};
#pragma unroll
  for (int half = 0; half < 2; ++half) {
    const u16* A = Ah[half] + (size_t)mc * 128;
#pragma unroll
    for (int s = 0; s < 4; ++s) {
      bf16x8 a = *(const bf16x8*)(A + s * 32 + quad * 8);  // A[m][k], k = s*32+quad*8+j
      int chunk = (half << 4) + (s << 2) + quad;
#pragma unroll
      for (int t = 0; t < 8; ++t) {
        int j = t * 16 + l16;
        bf16x8 b = *(const bf16x8*)(Wt + (size_t)j * 256 + chunk * 8);  // B[k][j] = Wt[j][k]
        acc[t] = __builtin_amdgcn_mfma_f32_16x16x32_bf16(a, b, acc[t], 0, 0, 0);
      }
    }
  }
  // C layout: col = lane&15, row = quad*4 + reg (m89-verified)
#pragma unroll
  for (int t = 0; t < 8; ++t) {
    int j = t * 16 + l16;
    float bj = bias[j];
#pragma unroll
    for (int r = 0; r < 4; ++r) {
      int mr = row0 + quad * 4 + r;
      if (mr < n) {
        float v = acc[t][r] + bj;
        Out[(size_t)mr * 128 + j] = f2bf(fmaxf(v, 0.f));
      }
    }
  }
}

// ---------------- pooling (two-phase, parallel) ----------------
#define PB_NODES 256
__global__ void pool_partial(const int* __restrict__ batch, const u32* __restrict__ h3,
                             float* __restrict__ pooled, int* __restrict__ gcnt, int n) {
  int wave = threadIdx.x >> 6, lane = threadIdx.x & 63;
  int start = blockIdx.x * PB_NODES;
  int end = min(start + PB_NODES, n);
  float a0 = 0.f, a1 = 0.f;
  int gcur = -1, cnt = 0;
  for (int i = start + wave; i < end; i += 4) {
    int g = batch[i];
    if (g != gcur) {
      if (gcur >= 0) {
        atomicAdd(&pooled[gcur * 128 + lane * 2], a0);
        atomicAdd(&pooled[gcur * 128 + lane * 2 + 1], a1);
        if (lane == 0) atomicAdd(&gcnt[gcur], cnt);
      }
      gcur = g; a0 = 0.f; a1 = 0.f; cnt = 0;
    }
    u32 v = h3[(size_t)i * 64 + lane];
    a0 += bf2f(v & 0xFFFFu);
    a1 += bf2f(v >> 16);
    cnt++;
  }
  if (gcur >= 0) {
    atomicAdd(&pooled[gcur * 128 + lane * 2], a0);
    atomicAdd(&pooled[gcur * 128 + lane * 2 + 1], a1);
    if (lane == 0) atomicAdd(&gcnt[gcur], cnt);
  }
}

__global__ void head_kernel(const float* __restrict__ pooled, const int* __restrict__ gcnt,
                            const float* __restrict__ Wfc, const float* __restrict__ bfc,
                            float* __restrict__ out) {
  __shared__ float lg[64][10];
  int t = threadIdx.x;
  if (t < 640) {
    int g = t / 10, c = t % 10;
    float inv = 1.f / (float)max(gcnt[g], 1);
    float acc = bfc[c];
    for (int k = 0; k < 128; ++k) acc += pooled[g * 128 + k] * inv * Wfc[k * 10 + c];
    lg[g][c] = acc;
  }
  __syncthreads();
  if (t < 640) {
    int g = t / 10, c = t % 10;
    float mx = -1e30f;
    for (int q = 0; q < 10; ++q) mx = fmaxf(mx, lg[g][q]);
    float se = 0.f;
    for (int q = 0; q < 10; ++q) se += expf(lg[g][q] - mx);
    out[g * 10 + c] = lg[g][c] - mx - logf(se);
  }
}

extern "C" void kernel_launch(void* const* d_in, const int* in_sizes, int n_in,
                              void* d_out, int out_size, void* d_ws, size_t ws_size,
                              hipStream_t stream) {
  const float* x   = (const float*)d_in[0];
  const int* ei    = (const int*)d_in[1];
  const int* batch = (const int*)d_in[2];
  const float* W1l = (const float*)d_in[3];
  const float* W1r = (const float*)d_in[4];
  const float* b1  = (const float*)d_in[5];
  const float* W2l = (const float*)d_in[6];
  const float* W2r = (const float*)d_in[7];
  const float* b2  = (const float*)d_in[8];
  const float* W3l = (const float*)d_in[9];
  const float* W3r = (const float*)d_in[10];
  const float* b3  = (const float*)d_in[11];
  const float* Wfc = (const float*)d_in[12];
  const float* bfc = (const float*)d_in[13];
  float* out = (float*)d_out;
  int N = in_sizes[0];
  int E = in_sizes[1] / 2;
  const int* src = ei;
  const int* dst = ei + E;

  char* p = (char*)d_ws;
  auto alloc = [&](size_t bytes) { void* r = (void*)p; p += (bytes + 255) & ~(size_t)255; return r; };
  int* roff   = (int*)alloc((size_t)(N + 1) * 4);
  int* csr    = (int*)alloc((size_t)E * 4);
  u32* bufA   = (u32*)alloc((size_t)N * 64 * 4);  // h1 -> mean3 -> h3 (aliases hist early)
  u32* bufB   = (u32*)alloc((size_t)N * 64 * 4);  // mean2 -> h2      (aliases part early)
  u16* wt2    = (u16*)alloc(32768 * 2);
  u16* wt3    = (u16*)alloc(32768 * 2);
  float* pooled = (float*)alloc(64 * 128 * 4);
  int* gcnt   = (int*)alloc(64 * 4);
  int* bsum   = (int*)alloc(1024 * 4);

  // CSR-build-time aliases (strictly before meanh1/agg write bufA/bufB)
  int nbuk = (N + 127) >> 7;          // 782
  int* hist = (int*)bufA;             // nbuk*HBLK ints = 800 KB
  u32* part = (u32*)bufB;             // E u32 = 6.4 MB
  int chunk = (E + HBLK - 1) / HBLK;  // 6250
  int nH = nbuk * HBLK;               // 200192
  int nbH = (nH + 255) / 256;         // 782

  hist_kernel<<<HBLK, 256, 0, stream>>>(dst, hist, E, nbuk, chunk);
  scan_local<<<nbH, 256, 0, stream>>>(hist, hist, bsum, nH);
  scan_fix<<<nbH, 256, 0, stream>>>(hist, bsum, nH);
  scatter2_kernel<<<HBLK, 256, 0, stream>>>(src, dst, hist, part, E, nbuk, chunk);
  scatter3_kernel<<<nbuk, 256, 0, stream>>>(part, hist, roff, csr, E, nbuk, N);
  wprep2_kernel<<<256, 256, 0, stream>>>(W2l, W2r, W3l, W3r, wt2, wt3, pooled, gcnt);
  meanh1_kernel<<<(N + 3) / 4, 256, 0, stream>>>(csr, roff, x, W1l, W1r, b1, bufA, N);
  agg_kernel<<<(N + 3) / 4, 256, 0, stream>>>(csr, roff, bufA, bufB, N);   // mean2 = agg(h1)
  mm_kernel<<<(N + 63) / 64, 256, 0, stream>>>((const u16*)bufB, (const u16*)bufA, wt2, b2, (u16*)bufB, N);
  agg_kernel<<<(N + 3) / 4, 256, 0, stream>>>(csr, roff, bufB, bufA, N);   // mean3 = agg(h2)
  mm_kernel<<<(N + 63) / 64, 256, 0, stream>>>((const u16*)bufA, (const u16*)bufB, wt3, b3, (u16*)bufA, N);
  pool_partial<<<(N + PB_NODES - 1) / PB_NODES, 256, 0, stream>>>(batch, bufA, pooled, gcnt, N);
  head_kernel<<<1, 640, 0, stream>>>(pooled, gcnt, Wfc, bfc, out);
}

// Round 8
// 364.859 us; speedup vs baseline: 1.4936x; 1.2415x over previous
//
#include <hip/hip_runtime.h>

typedef unsigned int u32;
typedef unsigned short u16;
typedef short bf16x8 __attribute__((ext_vector_type(8)));
typedef float f32x4 __attribute__((ext_vector_type(4)));
typedef u32 u32x4 __attribute__((ext_vector_type(4)));

#define HBLK 256  // blocks in hist/scatter2 pass

__device__ __forceinline__ u16 f2bf(float f) {
  u32 u = __float_as_uint(f);
  u = (u + 0x7FFFu + ((u >> 16) & 1u)) >> 16;
  return (u16)u;
}
__device__ __forceinline__ float bf2f(u32 h) { return __uint_as_float(h << 16); }

// ---------------- CSR build: bucket sort by dst ----------------
// bucket = dst >> 7 (128 nodes per bucket)
__global__ void hist_kernel(const int* __restrict__ dst, int* __restrict__ hist,
                            int E, int nbuk, int chunk) {
  __shared__ int h[1024];
  for (int i = threadIdx.x; i < nbuk; i += 256) h[i] = 0;
  __syncthreads();
  int b0 = blockIdx.x * chunk, b1 = min(b0 + chunk, E);
  for (int e = b0 + threadIdx.x; e < b1; e += 256)
    atomicAdd(&h[dst[e] >> 7], 1);
  __syncthreads();
  for (int i = threadIdx.x; i < nbuk; i += 256)
    hist[i * HBLK + blockIdx.x] = h[i];  // [bucket][block]
}

__global__ void scan_local(const int* __restrict__ in, int* __restrict__ out,
                           int* __restrict__ bsum, int n) {
  __shared__ int s[256];
  int tid = threadIdx.x;
  int i = blockIdx.x * 256 + tid;
  int v = (i < n) ? in[i] : 0;
  s[tid] = v;
  __syncthreads();
  for (int off = 1; off < 256; off <<= 1) {
    int t = (tid >= off) ? s[tid - off] : 0;
    __syncthreads();
    s[tid] += t;
    __syncthreads();
  }
  if (i < n) out[i] = s[tid] - v;  // local exclusive
  if (tid == 255) bsum[blockIdx.x] = s[255];
}

// merged: each block computes its global offset (reduce of bsum[0..b)) and adds
__global__ void scan_fix(int* __restrict__ a, const int* __restrict__ bsum, int n) {
  __shared__ int red[256];
  int tid = threadIdx.x, b = blockIdx.x;
  int s = 0;
  for (int k = tid; k < b; k += 256) s += bsum[k];
  red[tid] = s;
  __syncthreads();
  for (int off = 128; off; off >>= 1) {
    if (tid < off) red[tid] += red[tid + off];
    __syncthreads();
  }
  int i = b * 256 + tid;
  if (i < n) a[i] += red[0];
}

// partition edges into bucket-ordered part[]: packed (dstLow7<<25 | src)
__global__ void scatter2_kernel(const int* __restrict__ src, const int* __restrict__ dst,
                                const int* __restrict__ hist_s, u32* __restrict__ part,
                                int E, int nbuk, int chunk) {
  __shared__ int cur[1024];
  for (int i = threadIdx.x; i < nbuk; i += 256)
    cur[i] = hist_s[i * HBLK + blockIdx.x];
  __syncthreads();
  int b0 = blockIdx.x * chunk, b1 = min(b0 + chunk, E);
  for (int e = b0 + threadIdx.x; e < b1; e += 256) {
    int d = dst[e];
    int pos = atomicAdd(&cur[d >> 7], 1);
    part[pos] = (u32)src[e] | ((u32)(d & 127) << 25);
  }
}

// per-bucket: count per node, scan -> roff, scatter src into contiguous csr window
__global__ void scatter3_kernel(const u32* __restrict__ part, const int* __restrict__ hist_s,
                                int* __restrict__ roff, int* __restrict__ csr,
                                int E, int nbuk, int n) {
  int b = blockIdx.x;
  int tid = threadIdx.x;
  int base = hist_s[b * HBLK];
  int end = (b + 1 < nbuk) ? hist_s[(b + 1) * HBLK] : E;
  __shared__ int cnt[128];
  __shared__ int s[128];
  __shared__ int cur[128];
  if (tid < 128) cnt[tid] = 0;
  __syncthreads();
  for (int e = base + tid; e < end; e += 256)
    atomicAdd(&cnt[part[e] >> 25], 1);
  __syncthreads();
  if (tid < 128) s[tid] = cnt[tid];
  __syncthreads();
  for (int off = 1; off < 128; off <<= 1) {
    int t = (tid >= off && tid < 128) ? s[tid - off] : 0;
    __syncthreads();
    if (tid < 128) s[tid] += t;
    __syncthreads();
  }
  if (tid < 128) {
    int excl = s[tid] - cnt[tid];
    cur[tid] = base + excl;
    int node = b * 128 + tid;
    if (node < n) roff[node] = base + excl;
  }
  if (b == 0 && tid == 0) roff[n] = E;
  __syncthreads();
  for (int e = base + tid; e < end; e += 256) {
    u32 p = part[e];
    int pos = atomicAdd(&cur[p >> 25], 1);
    csr[pos] = (int)(p & 0x1FFFFFFu);
  }
}

// ---------------- layer 1: fused mean + rank-2 MLP ----------------
// one wave per node: 64-lane gather-reduce of x[src], then 2 features/lane
__global__ void meanh1_kernel(const int* __restrict__ csr, const int* __restrict__ roff,
                              const float* __restrict__ x,
                              const float* __restrict__ W1l, const float* __restrict__ W1r,
                              const float* __restrict__ b1, u32* __restrict__ h1, int n) {
  int wave = threadIdx.x >> 6, lane = threadIdx.x & 63;
  int i = blockIdx.x * 4 + wave;
  if (i >= n) return;
  int e0 = roff[i], e1 = roff[i + 1];
  float s = 0.f;
  for (int e = e0 + lane; e < e1; e += 64) s += x[csr[e]];
#pragma unroll
  for (int off = 1; off < 64; off <<= 1) s += __shfl_xor(s, off, 64);
  float m = s / (float)max(e1 - e0, 1);
  float xs = x[i];
  int j0 = lane * 2;
  float v0 = fmaxf(m * W1l[j0] + xs * W1r[j0] + b1[j0], 0.f);
  float v1 = fmaxf(m * W1l[j0 + 1] + xs * W1r[j0 + 1] + b1[j0 + 1], 0.f);
  h1[(size_t)i * 64 + lane] = (u32)f2bf(v0) | ((u32)f2bf(v1) << 16);
}

// pack both weight pairs into bf16 W^T layout; also zero pooled/gcnt
__global__ void wprep2_kernel(const float* __restrict__ W2l, const float* __restrict__ W2r,
                              const float* __restrict__ W3l, const float* __restrict__ W3r,
                              u16* __restrict__ wt2, u16* __restrict__ wt3,
                              float* __restrict__ pooled, int* __restrict__ gcnt) {
  int idx = blockIdx.x * 256 + threadIdx.x;  // 0..65535
  int which = idx >> 15, r = idx & 32767;
  int j = r >> 8, k = r & 255;
  if (which == 0) {
    float v = (k < 128) ? W2l[k * 128 + j] : W2r[(k - 128) * 128 + j];
    wt2[r] = f2bf(v);
  } else {
    float v = (k < 128) ? W3l[k * 128 + j] : W3r[(k - 128) * 128 + j];
    wt3[r] = f2bf(v);
  }
  if (idx < 8192) pooled[idx] = 0.f;
  if (idx < 64) gcnt[idx] = 0;
}

// generic mean-aggregation of bf16 feature rows over CSR.
// 4x16-lane groups each gather a different edge's 256B row via dwordx4;
// 4-deep unroll -> 16 edges in flight per wave (cascade 2-deep / 1-deep tail).
__global__ void agg_kernel(const int* __restrict__ csr, const int* __restrict__ roff,
                           const u32* __restrict__ hin, u32* __restrict__ outv, int n) {
  int wave = threadIdx.x >> 6, lane = threadIdx.x & 63;
  int i = blockIdx.x * 4 + wave;
  if (i >= n) return;
  int grp = lane >> 4, li = lane & 15;
  int e0 = roff[i], e1 = roff[i + 1];
  float a[8] = {};
  int e = e0 + grp;
  for (; e + 12 < e1; e += 16) {
    int s0 = csr[e], s1 = csr[e + 4], s2 = csr[e + 8], s3 = csr[e + 12];
    u32x4 v0 = *(const u32x4*)(hin + (size_t)s0 * 64 + li * 4);
    u32x4 v1 = *(const u32x4*)(hin + (size_t)s1 * 64 + li * 4);
    u32x4 v2 = *(const u32x4*)(hin + (size_t)s2 * 64 + li * 4);
    u32x4 v3 = *(const u32x4*)(hin + (size_t)s3 * 64 + li * 4);
#pragma unroll
    for (int w = 0; w < 4; ++w) {
      a[2 * w]     += bf2f(v0[w] & 0xFFFFu) + bf2f(v1[w] & 0xFFFFu) +
                      bf2f(v2[w] & 0xFFFFu) + bf2f(v3[w] & 0xFFFFu);
      a[2 * w + 1] += bf2f(v0[w] >> 16) + bf2f(v1[w] >> 16) +
                      bf2f(v2[w] >> 16) + bf2f(v3[w] >> 16);
    }
  }
  for (; e + 4 < e1; e += 8) {
    int s0 = csr[e], s1 = csr[e + 4];
    u32x4 v0 = *(const u32x4*)(hin + (size_t)s0 * 64 + li * 4);
    u32x4 v1 = *(const u32x4*)(hin + (size_t)s1 * 64 + li * 4);
#pragma unroll
    for (int w = 0; w < 4; ++w) {
      a[2 * w]     += bf2f(v0[w] & 0xFFFFu) + bf2f(v1[w] & 0xFFFFu);
      a[2 * w + 1] += bf2f(v0[w] >> 16) + bf2f(v1[w] >> 16);
    }
  }
  if (e < e1) {
    int s0 = csr[e];
    u32x4 v0 = *(const u32x4*)(hin + (size_t)s0 * 64 + li * 4);
#pragma unroll
    for (int w = 0; w < 4; ++w) {
      a[2 * w]     += bf2f(v0[w] & 0xFFFFu);
      a[2 * w + 1] += bf2f(v0[w] >> 16);
    }
  }
#pragma unroll
  for (int w = 0; w < 8; ++w) {
    a[w] += __shfl_xor(a[w], 16, 64);
    a[w] += __shfl_xor(a[w], 32, 64);
  }
  if (grp == 0) {
    float inv = 1.f / (float)max(e1 - e0, 1);
    u32x4 o;
#pragma unroll
    for (int w = 0; w < 4; ++w)
      o[w] = (u32)f2bf(a[2 * w] * inv) | ((u32)f2bf(a[2 * w + 1] * inv) << 16);
    *(u32x4*)(outv + (size_t)i * 64 + li * 4) = o;
  }
}

// h_next = relu([mean | h] @ [Wl; Wr] + b), MFMA 16x16x32 bf16.
// Weights staged in LDS (XOR-swizzled, conflict-free ds_read_b128).
// 1024-thread blocks: 64KB LDS x 2 blocks/CU = 32 waves/CU (max occupancy),
// staging amortized over 256 rows/block. In-place safe (per-wave rows).
__launch_bounds__(1024)
__global__ void mm_kernel(const u16* Aleft, const u16* Aright,
                          const u16* __restrict__ Wt, const float* __restrict__ bias,
                          u16* Out, int n) {
  __shared__ u16 wlds[32768];  // [j][256], 16B chunks XOR-swizzled by j
  for (int c = threadIdx.x; c < 4096; c += 1024) {
    int j = c >> 5, ch = c & 31;
    int swz = ch ^ (j & 31);
    *(u32x4*)(&wlds[j * 256 + swz * 8]) = *(const u32x4*)(&Wt[j * 256 + ch * 8]);
  }
  __syncthreads();
  int wave = threadIdx.x >> 6;
  int lane = threadIdx.x & 63;
  int quad = lane >> 4, l16 = lane & 15;
  int row0 = blockIdx.x * 256 + wave * 16;
  int m = row0 + l16;
  int mc = m < n ? m : (n - 1);
  f32x4 acc[8] = {};
  const u16* Ah[2] = {Aleft, Aright};
#pragma unroll
  for (int half = 0; half < 2; ++half) {
    const u16* A = Ah[half] + (size_t)mc * 128;
#pragma unroll
    for (int s = 0; s < 4; ++s) {
      bf16x8 a = *(const bf16x8*)(A + s * 32 + quad * 8);  // A[m][k], k = s*32+quad*8+j
      int chunk = (half << 4) + (s << 2) + quad;
#pragma unroll
      for (int t = 0; t < 8; ++t) {
        int j = t * 16 + l16;
        int swz = chunk ^ (j & 31);
        bf16x8 b = *(const bf16x8*)(&wlds[j * 256 + swz * 8]);  // B[k][j] = Wt[j][k]
        acc[t] = __builtin_amdgcn_mfma_f32_16x16x32_bf16(a, b, acc[t], 0, 0, 0);
      }
    }
  }
  // C layout: col = lane&15, row = quad*4 + reg (m89-verified)
#pragma unroll
  for (int t = 0; t < 8; ++t) {
    int j = t * 16 + l16;
    float bj = bias[j];
#pragma unroll
    for (int r = 0; r < 4; ++r) {
      int mr = row0 + quad * 4 + r;
      if (mr < n) {
        float v = acc[t][r] + bj;
        Out[(size_t)mr * 128 + j] = f2bf(fmaxf(v, 0.f));
      }
    }
  }
}

// ---------------- pooling (two-phase, parallel) ----------------
#define PB_NODES 256
__global__ void pool_partial(const int* __restrict__ batch, const u32* __restrict__ h3,
                             float* __restrict__ pooled, int* __restrict__ gcnt, int n) {
  int wave = threadIdx.x >> 6, lane = threadIdx.x & 63;
  int start = blockIdx.x * PB_NODES;
  int end = min(start + PB_NODES, n);
  float a0 = 0.f, a1 = 0.f;
  int gcur = -1, cnt = 0;
  for (int i = start + wave; i < end; i += 4) {
    int g = batch[i];
    if (g != gcur) {
      if (gcur >= 0) {
        atomicAdd(&pooled[gcur * 128 + lane * 2], a0);
        atomicAdd(&pooled[gcur * 128 + lane * 2 + 1], a1);
        if (lane == 0) atomicAdd(&gcnt[gcur], cnt);
      }
      gcur = g; a0 = 0.f; a1 = 0.f; cnt = 0;
    }
    u32 v = h3[(size_t)i * 64 + lane];
    a0 += bf2f(v & 0xFFFFu);
    a1 += bf2f(v >> 16);
    cnt++;
  }
  if (gcur >= 0) {
    atomicAdd(&pooled[gcur * 128 + lane * 2], a0);
    atomicAdd(&pooled[gcur * 128 + lane * 2 + 1], a1);
    if (lane == 0) atomicAdd(&gcnt[gcur], cnt);
  }
}

__global__ void head_kernel(const float* __restrict__ pooled, const int* __restrict__ gcnt,
                            const float* __restrict__ Wfc, const float* __restrict__ bfc,
                            float* __restrict__ out) {
  __shared__ float lg[64][10];
  int t = threadIdx.x;
  if (t < 640) {
    int g = t / 10, c = t % 10;
    float inv = 1.f / (float)max(gcnt[g], 1);
    float acc = bfc[c];
    for (int k = 0; k < 128; ++k) acc += pooled[g * 128 + k] * inv * Wfc[k * 10 + c];
    lg[g][c] = acc;
  }
  __syncthreads();
  if (t < 640) {
    int g = t / 10, c = t % 10;
    float mx = -1e30f;
    for (int q = 0; q < 10; ++q) mx = fmaxf(mx, lg[g][q]);
    float se = 0.f;
    for (int q = 0; q < 10; ++q) se += expf(lg[g][q] - mx);
    out[g * 10 + c] = lg[g][c] - mx - logf(se);
  }
}

extern "C" void kernel_launch(void* const* d_in, const int* in_sizes, int n_in,
                              void* d_out, int out_size, void* d_ws, size_t ws_size,
                              hipStream_t stream) {
  const float* x   = (const float*)d_in[0];
  const int* ei    = (const int*)d_in[1];
  const int* batch = (const int*)d_in[2];
  const float* W1l = (const float*)d_in[3];
  const float* W1r = (const float*)d_in[4];
  const float* b1  = (const float*)d_in[5];
  const float* W2l = (const float*)d_in[6];
  const float* W2r = (const float*)d_in[7];
  const float* b2  = (const float*)d_in[8];
  const float* W3l = (const float*)d_in[9];
  const float* W3r = (const float*)d_in[10];
  const float* b3  = (const float*)d_in[11];
  const float* Wfc = (const float*)d_in[12];
  const float* bfc = (const float*)d_in[13];
  float* out = (float*)d_out;
  int N = in_sizes[0];
  int E = in_sizes[1] / 2;
  const int* src = ei;
  const int* dst = ei + E;

  char* p = (char*)d_ws;
  auto alloc = [&](size_t bytes) { void* r = (void*)p; p += (bytes + 255) & ~(size_t)255; return r; };
  int* roff   = (int*)alloc((size_t)(N + 1) * 4);
  int* csr    = (int*)alloc((size_t)E * 4);
  u32* bufA   = (u32*)alloc((size_t)N * 64 * 4);  // h1 -> mean3 -> h3 (aliases hist early)
  u32* bufB   = (u32*)alloc((size_t)N * 64 * 4);  // mean2 -> h2      (aliases part early)
  u16* wt2    = (u16*)alloc(32768 * 2);
  u16* wt3    = (u16*)alloc(32768 * 2);
  float* pooled = (float*)alloc(64 * 128 * 4);
  int* gcnt   = (int*)alloc(64 * 4);
  int* bsum   = (int*)alloc(1024 * 4);

  // CSR-build-time aliases (strictly before meanh1/agg write bufA/bufB)
  int nbuk = (N + 127) >> 7;          // 782
  int* hist = (int*)bufA;             // nbuk*HBLK ints = 800 KB
  u32* part = (u32*)bufB;             // E u32 = 6.4 MB
  int chunk = (E + HBLK - 1) / HBLK;  // 6250
  int nH = nbuk * HBLK;               // 200192
  int nbH = (nH + 255) / 256;         // 782

  hist_kernel<<<HBLK, 256, 0, stream>>>(dst, hist, E, nbuk, chunk);
  scan_local<<<nbH, 256, 0, stream>>>(hist, hist, bsum, nH);
  scan_fix<<<nbH, 256, 0, stream>>>(hist, bsum, nH);
  scatter2_kernel<<<HBLK, 256, 0, stream>>>(src, dst, hist, part, E, nbuk, chunk);
  scatter3_kernel<<<nbuk, 256, 0, stream>>>(part, hist, roff, csr, E, nbuk, N);
  wprep2_kernel<<<256, 256, 0, stream>>>(W2l, W2r, W3l, W3r, wt2, wt3, pooled, gcnt);
  meanh1_kernel<<<(N + 3) / 4, 256, 0, stream>>>(csr, roff, x, W1l, W1r, b1, bufA, N);
  agg_kernel<<<(N + 3) / 4, 256, 0, stream>>>(csr, roff, bufA, bufB, N);   // mean2 = agg(h1)
  mm_kernel<<<(N + 255) / 256, 1024, 0, stream>>>((const u16*)bufB, (const u16*)bufA, wt2, b2, (u16*)bufB, N);
  agg_kernel<<<(N + 3) / 4, 256, 0, stream>>>(csr, roff, bufB, bufA, N);   // mean3 = agg(h2)
  mm_kernel<<<(N + 255) / 256, 1024, 0, stream>>>((const u16*)bufA, (const u16*)bufB, wt3, b3, (u16*)bufA, N);
  pool_partial<<<(N + PB_NODES - 1) / PB_NODES, 256, 0, stream>>>(batch, bufA, pooled, gcnt, N);
  head_kernel<<<1, 640, 0, stream>>>(pooled, gcnt, Wfc, bfc, out);
}